// Round 3
// baseline (100.100 us; speedup 1.0000x reference)
//
#include <hip/hip_runtime.h>

// features (B=16, C=256, H=64, W=64) fp32 -> per-pixel channel stats -> 3->16->1 MLP.
// Memory-bound: 64 MiB read, 256 KB write. HBM floor ~10.7 us at 6.3 TB/s.
//
// R3 change vs R2: DRAM-page-friendly reads. Block = (b, 4 h-rows), 1024 thr
// = 64 float4-pixel-slots (4 rows x 16) x 16 channel-groups (16 ch each).
// A wave's 64 lanes read 64 consecutive float4 = ONE contiguous 1 KB segment
// per load instruction (vs 4x 256 B scattered in R2), so each HBM page is
// consumed in one activation. Grid = 16*16 = 256 blocks = 1/CU, 16 waves/CU.

#define C_DIM 256
#define PLANE4 1024   // H*W/4 = channel-plane stride in float4

__global__ __launch_bounds__(1024, 4) void fis_importance_kernel(
    const float* __restrict__ features,
    const float* __restrict__ W1,   // (3,16) row-major: W1[i*16+o]
    const float* __restrict__ b1,   // (16,)
    const float* __restrict__ W2,   // (16,)
    const float* __restrict__ b2,   // (1,)
    float* __restrict__ out)        // (B,H,W) flat
{
    const int blk = blockIdx.x;          // 0..255
    const int b   = blk >> 4;            // batch
    const int h0  = (blk & 15) << 2;     // first of 4 h-rows
    const int tid = threadIdx.x;         // 0..1023
    const int p4  = tid & 63;            // float4 slot within 4-row tile (0..63)
    const int cg  = tid >> 6;            // channel group 0..15 (16 ch each)

    // float4 index of (b, c = cg*16, h0, w=0) + p4  -> lanes read 1 KB contig
    const float4* fptr = reinterpret_cast<const float4*>(features)
        + ((size_t)(b * C_DIM + cg * 16) * 64 + h0) * 16 + p4;

    float4 s = make_float4(0.f, 0.f, 0.f, 0.f);   // sum over this cg's 16 ch
    float4 q = make_float4(0.f, 0.f, 0.f, 0.f);   // sum of squares

#pragma unroll
    for (int batch = 0; batch < 4; ++batch) {
        float4 v0 = fptr[(size_t)(batch * 4 + 0) * PLANE4];
        float4 v1 = fptr[(size_t)(batch * 4 + 1) * PLANE4];
        float4 v2 = fptr[(size_t)(batch * 4 + 2) * PLANE4];
        float4 v3 = fptr[(size_t)(batch * 4 + 3) * PLANE4];
        s.x += v0.x + v1.x + v2.x + v3.x;
        s.y += v0.y + v1.y + v2.y + v3.y;
        s.z += v0.z + v1.z + v2.z + v3.z;
        s.w += v0.w + v1.w + v2.w + v3.w;
        q.x += v0.x*v0.x + v1.x*v1.x + v2.x*v2.x + v3.x*v3.x;
        q.y += v0.y*v0.y + v1.y*v1.y + v2.y*v2.y + v3.y*v3.y;
        q.z += v0.z*v0.z + v1.z*v1.z + v2.z*v2.z + v3.z*v3.z;
        q.w += v0.w*v0.w + v1.w*v1.w + v2.w*v2.w + v3.w*v3.w;
    }

    __shared__ float4 s_sum[16][64];  // [cg][p4]  16 KB
    __shared__ float4 s_sq [16][64];  //           16 KB
    s_sum[cg][p4] = s;
    s_sq [cg][p4] = q;
    __syncthreads();

    if (tid < 256) {
        const int p = tid;            // pixel within 4x64 tile

        float sum = 0.f, sq = 0.f;
#pragma unroll
        for (int g = 0; g < 16; ++g) {
            // addr = g*1024B + p*4B: wave lanes hit 64 consecutive floats
            // = 2 lanes/bank -> conflict-free (m136)
            sum += reinterpret_cast<const float*>(&s_sum[g][p >> 2])[p & 3];
            sq  += reinterpret_cast<const float*>(&s_sq [g][p >> 2])[p & 3];
        }

        const float inv_c  = 1.0f / 256.0f;
        const float inv_c1 = 1.0f / 255.0f;

        float mag = sqrtf(sq * inv_c);                       // ||f||/sqrt(C)
        float var = (sq - sum * sum * inv_c) * inv_c1;       // unbiased
        var = fmaxf(var, 0.f);
        float stdv = sqrtf(var);

        mag = fminf(fmaxf(mag, 0.f), 1.f);
        float varc = fminf(var,  1.f);
        float grad = fminf(stdv, 1.f);

        // MLP: hk = relu(x @ W1 + b1); o = sigmoid(h @ W2 + b2)
        float o = b2[0];
#pragma unroll
        for (int k = 0; k < 16; ++k) {
            float hk = b1[k] + mag * W1[k] + varc * W1[16 + k] + grad * W1[32 + k];
            hk = fmaxf(hk, 0.f);
            o += hk * W2[k];
        }
        // out base (b*64 + h0)*64 + p : 256 threads store 1 KB contiguous
        out[((b * 64 + h0) * 64) + p] = 1.f / (1.f + __expf(-o));
    }
}

extern "C" void kernel_launch(void* const* d_in, const int* in_sizes, int n_in,
                              void* d_out, int out_size, void* d_ws, size_t ws_size,
                              hipStream_t stream) {
    const float* features = (const float*)d_in[0];
    const float* W1 = (const float*)d_in[1];
    const float* b1 = (const float*)d_in[2];
    const float* W2 = (const float*)d_in[3];
    const float* b2 = (const float*)d_in[4];
    float* out = (float*)d_out;

    // grid = B * H/4 = 16*16 = 256 blocks (1 per CU), 1024 threads each
    fis_importance_kernel<<<256, 1024, 0, stream>>>(features, W1, b1, W2, b2, out);
}

// Round 4
// 95.997 us; speedup vs baseline: 1.0427x; 1.0427x over previous
//
#include <hip/hip_runtime.h>

// features (B=16, C=256, H=64, W=64) fp32 -> per-pixel channel stats -> 3->16->1 MLP.
// Memory-bound: 64 MiB read, 256 KB write. HBM floor ~10.7 us at 6.3 TB/s;
// harness reset traffic adds a fixed ~73+ us to dur_us (268 MB ws poison fill
// = 42 us observed + 134 MB input restore ~21 us + gaps).
//
// R4 change: maximize memory-level parallelism. Each thread issues ALL 16
// channel-plane loads back-to-back (no accumulation between them), so 16
// wave-loads are outstanding per wave (vs 4 in R1-R3). 256 thr/block
// (16 w4-slots x 16 channel-groups), grid = B*H = 1024. ~90 VGPR -> 4
// waves/EU, 4 blocks/CU, 16 waves/CU.

#define C_DIM 256
#define PLANE4 1024   // H*W/4 = channel-plane stride in float4

__global__ __launch_bounds__(256, 4) void fis_importance_kernel(
    const float* __restrict__ features,
    const float* __restrict__ W1,   // (3,16) row-major: W1[i*16+o]
    const float* __restrict__ b1,   // (16,)
    const float* __restrict__ W2,   // (16,)
    const float* __restrict__ b2,   // (1,)
    float* __restrict__ out)        // (B,H,W) flat
{
    const int row = blockIdx.x;          // 0..B*H-1  (= b*64 + h)
    const int tid = threadIdx.x;         // 0..255
    const int w4  = tid & 15;            // float4 index along W
    const int cg  = tid >> 4;            // channel group 0..15 (16 ch each)

    const int b = row >> 6;
    const int h = row & 63;

    const float4* fptr = reinterpret_cast<const float4*>(features)
        + ((size_t)(b * C_DIM + cg * 16) * 64 + h) * 16 + w4;

    // Issue all 16 loads before any FLOP: 16 outstanding wave-loads.
    float4 v[16];
#pragma unroll
    for (int i = 0; i < 16; ++i)
        v[i] = fptr[(size_t)i * PLANE4];

    float4 s = make_float4(0.f, 0.f, 0.f, 0.f);
    float4 q = make_float4(0.f, 0.f, 0.f, 0.f);
#pragma unroll
    for (int i = 0; i < 16; ++i) {
        s.x += v[i].x; s.y += v[i].y; s.z += v[i].z; s.w += v[i].w;
        q.x += v[i].x * v[i].x; q.y += v[i].y * v[i].y;
        q.z += v[i].z * v[i].z; q.w += v[i].w * v[i].w;
    }

    __shared__ float4 s_sum[16][16];  // [cg][w4]  4 KB
    __shared__ float4 s_sq [16][16];  //           4 KB
    s_sum[cg][w4] = s;
    s_sq [cg][w4] = q;
    __syncthreads();

    if (tid < 64) {
        const int w   = tid;
        const int ww4 = w >> 2;
        const int j   = w & 3;

        float sum = 0.f, sq = 0.f;
#pragma unroll
        for (int g = 0; g < 16; ++g) {
            // fixed g: threads 0..63 read consecutive floats -> 2 lanes/bank, free
            sum += reinterpret_cast<const float*>(&s_sum[g][ww4])[j];
            sq  += reinterpret_cast<const float*>(&s_sq [g][ww4])[j];
        }

        const float inv_c  = 1.0f / 256.0f;
        const float inv_c1 = 1.0f / 255.0f;

        float mag = sqrtf(sq * inv_c);                       // ||f||/sqrt(C)
        float var = (sq - sum * sum * inv_c) * inv_c1;       // unbiased
        var = fmaxf(var, 0.f);
        float stdv = sqrtf(var);

        mag = fminf(fmaxf(mag, 0.f), 1.f);
        float varc = fminf(var,  1.f);
        float grad = fminf(stdv, 1.f);

        float o = b2[0];
#pragma unroll
        for (int k = 0; k < 16; ++k) {
            float hk = b1[k] + mag * W1[k] + varc * W1[16 + k] + grad * W1[32 + k];
            hk = fmaxf(hk, 0.f);
            o += hk * W2[k];
        }
        out[row * 64 + w] = 1.f / (1.f + __expf(-o));
    }
}

extern "C" void kernel_launch(void* const* d_in, const int* in_sizes, int n_in,
                              void* d_out, int out_size, void* d_ws, size_t ws_size,
                              hipStream_t stream) {
    const float* features = (const float*)d_in[0];
    const float* W1 = (const float*)d_in[1];
    const float* b1 = (const float*)d_in[2];
    const float* W2 = (const float*)d_in[3];
    const float* b2 = (const float*)d_in[4];
    float* out = (float*)d_out;

    fis_importance_kernel<<<1024, 256, 0, stream>>>(features, W1, b1, W2, b2, out);
}